// Round 1
// 417.838 us; speedup vs baseline: 1.0162x; 1.0162x over previous
//
#include <hip/hip_runtime.h>

typedef __bf16 bf16;
typedef __bf16 bf16x4 __attribute__((ext_vector_type(4)));
typedef __bf16 bf16x8 __attribute__((ext_vector_type(8)));
typedef float f32x4 __attribute__((ext_vector_type(4)));

#define K_TOT 1024    // D_IN
#define N_TOT 512     // H1
#define T_SEQ 2048
#define NB 32

// ---------------------------------------------------------------------------
// async global->LDS, 16B per lane. LDS dest = wave-uniform base + lane*16.
// ---------------------------------------------------------------------------
__device__ __forceinline__ void async16(const void* g, void* l) {
    __builtin_amdgcn_global_load_lds(
        (const __attribute__((address_space(1))) unsigned int*)g,
        (__attribute__((address_space(3))) unsigned int*)l, 16, 0, 0);
}

// ---------------------------------------------------------------------------
// Kernel 0a: W1 [1024,512] fp32 -> W1T [512,1024] bf16 (transposed)
// ---------------------------------------------------------------------------
__global__ __launch_bounds__(256) void transpose_w1(const float* __restrict__ W1,
                                                    bf16* __restrict__ W1T) {
    __shared__ float tile[32][33];
    const int t = threadIdx.x;
    const int k0 = blockIdx.x * 32;
    const int n0 = blockIdx.y * 32;
#pragma unroll
    for (int p = 0; p < 4; p++) {
        int kl = p * 8 + (t >> 5);
        int nl = t & 31;
        tile[kl][nl] = W1[(k0 + kl) * 512 + n0 + nl];
    }
    __syncthreads();
#pragma unroll
    for (int p = 0; p < 4; p++) {
        int nl = p * 8 + (t >> 5);
        int kl = t & 31;
        W1T[(n0 + nl) * 1024 + k0 + kl] = (bf16)tile[kl][nl];
    }
}

// ---------------------------------------------------------------------------
// Kernel 0b (prep): fold layers 2+3 into v[] AND build the compacted live-tile
// list from seq_len. Tile i (i = b*16 + j) covers rows [i*128, i*128+128) of
// the flattened [B*T] row space; it is live iff j*128 < seq_len[b] (rows at
// t >= seq_len are masked out of the top-k by the reference -> dead work).
// tiles[0] = live count, tiles[1..] = live tile ids (dense, sample-major).
// ---------------------------------------------------------------------------
__global__ __launch_bounds__(512) void prep(const float* __restrict__ W2,
                                            const float* __restrict__ b2,
                                            const float* __restrict__ W3,
                                            const float* __restrict__ b3,
                                            const int* __restrict__ seq_len,
                                            float* __restrict__ v,
                                            int* __restrict__ tiles) {
    const int t = threadIdx.x;
    float s = 0.f;
#pragma unroll
    for (int c = 0; c < 32; c++) s += W2[t * 32 + c] * W3[c];
    v[t] = s;
    if (t == 0) {
        float cc = b3[0];
        for (int c = 0; c < 32; c++) cc += b2[c] * W3[c];
        v[512] = cc;
    }
    // live-tile compaction (32 samples x 16 tiles)
    __shared__ int nb[32], off[32];
    if (t < 32) nb[t] = (seq_len[t] + 127) >> 7;   // ceil(L/128), in [1,16]
    __syncthreads();
    if (t == 0) {
        int a = 0;
        for (int i = 0; i < 32; i++) { off[i] = a; a += nb[i]; }
        tiles[0] = a;
    }
    __syncthreads();
    const int b = t >> 4, j = t & 15;
    if (j < nb[b]) tiles[1 + off[b] + j] = t;
}

// ---------------------------------------------------------------------------
// Kernel 1 (fused, double-buffered, ONE barrier per K-iter):
// per block: 128 rows x full N=512; logits = sigmoid(sum relu(h)*v + c).
// LDS 160 KB = 2 x (As 16 KB + Bs 64 KB). Prefetch k+1 issued right after
// the barrier, drained one full MFMA phase (~2500 cyc) later -> latency hidden
// even at 1 block/CU.
// Ragged skip: block i handles live tile tiles[1+i]; blocks >= tiles[0] exit.
// Compaction (not raw early-exit) keeps ~1 live tile per CU — raw exit pairs
// block i with i+256 which shares the same within-sample tile index j, so
// j=0 CUs would always carry 2 live blocks (tail = no win).
// ---------------------------------------------------------------------------
__device__ __forceinline__ int sw_idx(int row, int e) {  // elem idx into [row][64]
    return row * 64 + (((e >> 3) ^ (row & 7)) << 3) + (e & 7);
}

__global__ __launch_bounds__(512, 2) void gemm_fused(const float* __restrict__ A,
                                                     const bf16* __restrict__ W1T,
                                                     const float* __restrict__ b1,
                                                     const float* __restrict__ v,
                                                     const int* __restrict__ tiles,
                                                     float* __restrict__ logits) {
    __shared__ bf16 smem[2][(128 + 512) * 64];  // 2 x 80 KB = 160 KB (CU max)

    const int nact = tiles[0];
    if ((int)blockIdx.x >= nact) return;         // dead tile: no HBM traffic
    const int m0 = tiles[1 + blockIdx.x] * 128;

    const int t = threadIdx.x;
    const int wave = t >> 6, lane = t & 63;
    const int q = lane >> 4, l15 = lane & 15;
    const int wm = wave >> 2, wn = wave & 3;   // 2 x 4 wave grid, wave tile 64x128

    // A staging: thread t -> row t>>2, c = t&3. Load p: float idx c*4 + p*16.
    // Per instruction: 4 consecutive lanes cover 64 contiguous bytes of a row
    // -> 16 lines/instr in contiguous runs.
    const int arow = t >> 2, ac = t & 3;
    const float* agp = A + (size_t)(m0 + arow) * K_TOT + ac * 4;

    // B async staging: lane -> n-row wave*64 + (lane>>3), global 16B chunk
    // XOR-permuted so linear LDS (base + lane*16) ends up swizzled.
    const int bl_row = wave * 64 + (lane >> 3);
    const int bl_chunk = (lane & 7) ^ ((lane >> 3) & 7);
    const bf16* bgp = W1T + (size_t)bl_row * K_TOT + bl_chunk * 8;

    f32x4 acc[4][8] = {};
    float4 av[4];

    auto loadA = [&](int k0) {
#pragma unroll
        for (int p = 0; p < 4; p++) av[p] = *(const float4*)(agp + k0 + p * 16);
    };
    auto asyncB = [&](int k0, int b) {
        bf16* bs = smem[b] + 128 * 64;
#pragma unroll
        for (int j = 0; j < 8; j++)
            async16(bgp + k0 + (size_t)j * 8 * K_TOT, bs + (wave * 64 + j * 8) * 64);
    };
    auto writeA = [&](int b) {
        bf16* as = smem[b];
#pragma unroll
        for (int p = 0; p < 4; p++) {
            bf16x4 w;
            w[0] = (bf16)av[p].x; w[1] = (bf16)av[p].y;
            w[2] = (bf16)av[p].z; w[3] = (bf16)av[p].w;
            int chunk = 2 * p + (ac >> 1);                 // global 8-elem chunk
            int idx = arow * 64 + ((chunk ^ (arow & 7)) << 3) + (ac & 1) * 4;
            *(bf16x4*)(&as[idx]) = w;
        }
    };
    auto mfma_phase = [&](int b) {
        const bf16* as = smem[b];
        const bf16* bs = smem[b] + 128 * 64;
#pragma unroll
        for (int kk = 0; kk < 64; kk += 32) {
            const int e = kk + q * 8;
            bf16x8 af[4], bfv[8];
#pragma unroll
            for (int mi = 0; mi < 4; mi++)
                af[mi] = *(const bf16x8*)(&as[sw_idx(wm * 64 + mi * 16 + l15, e)]);
#pragma unroll
            for (int ni = 0; ni < 8; ni++)
                bfv[ni] = *(const bf16x8*)(&bs[sw_idx(wn * 128 + ni * 16 + l15, e)]);
#pragma unroll
            for (int mi = 0; mi < 4; mi++)
#pragma unroll
                for (int ni = 0; ni < 8; ni++)
                    acc[mi][ni] = __builtin_amdgcn_mfma_f32_16x16x32_bf16(
                        af[mi], bfv[ni], acc[mi][ni], 0, 0, 0);
        }
    };

    // ---- preload k=0 into buffer 0 ----
    loadA(0);
    asyncB(0, 0);
    writeA(0);          // compiler: vmcnt(8) -> waits A only, B stays in flight
    __syncthreads();    // drains B(0)

#pragma unroll 1
    for (int k = 0; k < 16; k++) {
        const int buf = k & 1, nxt = buf ^ 1;
        if (k < 15) {
            loadA((k + 1) * 64);     // A(k+1) -> VGPR   (overlaps MFMA below)
            asyncB((k + 1) * 64, nxt);  // B(k+1) -> LDS async
        }
        mfma_phase(buf);             // ~2500 cyc/CU: covers all load latency
        if (k < 15) writeA(nxt);     // vmcnt wait lands after MFMA -> ~free
        __syncthreads();             // single barrier per iter; drains B(k+1)
    }

    // ---- Epilogue: logit[m] = sigmoid( sum_cols relu(acc + b1)*v + c ) ----
    float bb[8], vv[8];
#pragma unroll
    for (int ni = 0; ni < 8; ni++) {
        int col = wn * 128 + ni * 16 + l15;
        bb[ni] = b1[col];
        vv[ni] = v[col];
    }
    const float cconst = v[512];

    __syncthreads();
    float* part = (float*)smem;      // [128][4] per-row partials per wn

#pragma unroll
    for (int mi = 0; mi < 4; mi++) {
#pragma unroll
        for (int r = 0; r < 4; r++) {
            float s = 0.f;
#pragma unroll
            for (int ni = 0; ni < 8; ni++)
                s += fmaxf(acc[mi][ni][r] + bb[ni], 0.f) * vv[ni];
            s += __shfl_xor(s, 1);
            s += __shfl_xor(s, 2);
            s += __shfl_xor(s, 4);
            s += __shfl_xor(s, 8);
            if (l15 == 0) {
                int row = wm * 64 + mi * 16 + q * 4 + r;
                part[row * 4 + wn] = s;
            }
        }
    }
    __syncthreads();
    if (t < 128) {
        float s = part[t * 4] + part[t * 4 + 1] + part[t * 4 + 2] + part[t * 4 + 3] + cconst;
        logits[m0 + t] = 1.f / (1.f + __expf(-s));
    }
}

// ---------------------------------------------------------------------------
// Kernel 3: per-sample ragged top-k mean (exact; binary search on float bits).
// Only reads logits[i] for i < seq_len[b] -> every row it touches came from a
// live tile (tile i>>7 is live whenever i < L), so the ragged skip is exact.
// ---------------------------------------------------------------------------
__global__ __launch_bounds__(256) void topk_mean(const float* __restrict__ logits,
                                                 const int* __restrict__ seq_len,
                                                 float* __restrict__ out) {
    __shared__ float vals[T_SEQ];
    __shared__ int redi[4];
    __shared__ float redf[4];
    const int b = blockIdx.x, t = threadIdx.x;
    const int lane = t & 63, wave = t >> 6;
    const int L = seq_len[b];
    const int k = (L >> 4) + 1;
    const float* p = logits + b * T_SEQ;
    for (int i = t; i < L; i += 256) vals[i] = p[i];
    __syncthreads();

    unsigned lo = 0u, hi = 0x3f800000u;  // (0, 1.0]
    while (lo < hi) {
        unsigned mid = lo + ((hi - lo + 1) >> 1);
        float thr = __uint_as_float(mid);
        int cnt = 0;
        for (int i = t; i < L; i += 256) cnt += (vals[i] >= thr) ? 1 : 0;
#pragma unroll
        for (int m = 32; m >= 1; m >>= 1) cnt += __shfl_xor(cnt, m);
        if (lane == 0) redi[wave] = cnt;
        __syncthreads();
        int total = redi[0] + redi[1] + redi[2] + redi[3];
        __syncthreads();
        if (total >= k) lo = mid; else hi = mid - 1;
    }
    const float thr = __uint_as_float(lo);

    int cnt = 0; float sum = 0.f;
    for (int i = t; i < L; i += 256) {
        float x = vals[i];
        if (x > thr) { cnt += 1; sum += x; }
    }
#pragma unroll
    for (int m = 32; m >= 1; m >>= 1) { cnt += __shfl_xor(cnt, m); sum += __shfl_xor(sum, m); }
    if (lane == 0) { redi[wave] = cnt; redf[wave] = sum; }
    __syncthreads();
    if (t == 0) {
        int cgt = redi[0] + redi[1] + redi[2] + redi[3];
        float sgt = redf[0] + redf[1] + redf[2] + redf[3];
        out[b] = (sgt + (float)(k - cgt) * thr) / (float)k;
    }
}

// ---------------------------------------------------------------------------
extern "C" void kernel_launch(void* const* d_in, const int* in_sizes, int n_in,
                              void* d_out, int out_size, void* d_ws, size_t ws_size,
                              hipStream_t stream) {
    const float* avf = (const float*)d_in[0];
    const float* W1  = (const float*)d_in[1];
    const float* b1  = (const float*)d_in[2];
    const float* W2  = (const float*)d_in[3];
    const float* b2  = (const float*)d_in[4];
    const float* W3  = (const float*)d_in[5];
    const float* b3  = (const float*)d_in[6];
    const int* seq_len = (const int*)d_in[7];
    float* out = (float*)d_out;

    char* ws = (char*)d_ws;
    bf16*  W1T    = (bf16*)ws;                          // 1 MB
    float* v      = (float*)(ws + (1 << 20));           // 513 floats
    int*   tiles  = (int*)(ws + (1 << 20) + 4096);      // 1 + 512 ints
    float* logits = (float*)(ws + (1 << 20) + 8192);    // 256 KB

    transpose_w1<<<dim3(32, 16), 256, 0, stream>>>(W1, W1T);
    prep<<<1, 512, 0, stream>>>(W2, b2, W3, b3, seq_len, v, tiles);
    gemm_fused<<<512, 512, 0, stream>>>(avf, W1T, b1, v, tiles, logits);
    topk_mean<<<NB, 256, 0, stream>>>(logits, seq_len, out);
}

// Round 2
// 411.650 us; speedup vs baseline: 1.0314x; 1.0150x over previous
//
#include <hip/hip_runtime.h>

typedef __bf16 bf16;
typedef __bf16 bf16x4 __attribute__((ext_vector_type(4)));
typedef __bf16 bf16x8 __attribute__((ext_vector_type(8)));
typedef float f32x4 __attribute__((ext_vector_type(4)));

#define K_TOT 1024    // D_IN
#define N_TOT 512     // H1
#define T_SEQ 2048
#define NB 32

// ---------------------------------------------------------------------------
// async global->LDS, 16B per lane. LDS dest = wave-uniform base + lane*16.
// ---------------------------------------------------------------------------
__device__ __forceinline__ void async16(const void* g, void* l) {
    __builtin_amdgcn_global_load_lds(
        (const __attribute__((address_space(1))) unsigned int*)g,
        (__attribute__((address_space(3))) unsigned int*)l, 16, 0, 0);
}

// ---------------------------------------------------------------------------
// Kernel 0 (merged): W1 [1024,512] fp32 -> W1T [512,1024] bf16, AND (block 0)
// the prep work: fold layers 2+3 into v[], build compacted live-tile list,
// zero per-sample completion counters.
// Tile i (i = b*16 + j) covers rows [i*128, i*128+128); live iff j*128 < L_b
// (rows at t >= seq_len are masked out of the ref top-k -> dead work).
// tiles[0] = live count, tiles[1..] = live tile ids (sample-major).
// ---------------------------------------------------------------------------
__global__ __launch_bounds__(256) void transpose_prep(
        const float* __restrict__ W1, bf16* __restrict__ W1T,
        const float* __restrict__ W2, const float* __restrict__ b2,
        const float* __restrict__ W3, const float* __restrict__ b3,
        const int* __restrict__ seq_len,
        float* __restrict__ v, int* __restrict__ tiles, int* __restrict__ done) {
    __shared__ float tile[32][33];
    __shared__ int nb2[32], off2[32];
    const int t = threadIdx.x;
    const int k0 = blockIdx.x * 32;
    const int n0 = blockIdx.y * 32;
#pragma unroll
    for (int p = 0; p < 4; p++) {
        int kl = p * 8 + (t >> 5);
        int nl = t & 31;
        tile[kl][nl] = W1[(k0 + kl) * 512 + n0 + nl];
    }
    __syncthreads();
#pragma unroll
    for (int p = 0; p < 4; p++) {
        int nl = p * 8 + (t >> 5);
        int kl = t & 31;
        W1T[(n0 + nl) * 1024 + k0 + kl] = (bf16)tile[kl][nl];
    }

    if (blockIdx.x == 0 && blockIdx.y == 0) {   // block-uniform branch
        // v[h] = sum_c W2[h][c]*W3[c];  v[512] = b2.W3 + b3
        for (int h = t; h < 512; h += 256) {
            float s = 0.f;
#pragma unroll
            for (int c = 0; c < 32; c++) s += W2[h * 32 + c] * W3[c];
            v[h] = s;
        }
        if (t == 0) {
            float cc = b3[0];
            for (int c = 0; c < 32; c++) cc += b2[c] * W3[c];
            v[512] = cc;
        }
        if (t < 32) {
            nb2[t] = (seq_len[t] + 127) >> 7;   // ceil(L/128), in [1,16]
            done[t] = 0;                        // completion counters (ws is poisoned)
        }
        __syncthreads();
        if (t == 0) {
            int a = 0;
            for (int i = 0; i < 32; i++) { off2[i] = a; a += nb2[i]; }
            tiles[0] = a;
        }
        __syncthreads();
        for (int idx = t; idx < 512; idx += 256) {
            int b = idx >> 4, j = idx & 15;
            if (j < nb2[b]) tiles[1 + off2[b] + j] = idx;
        }
    }
}

// ---------------------------------------------------------------------------
// Kernel 1 (fused gemm + MLP epilogue + per-sample top-k):
// per block: 128 rows x full N=512; logits = sigmoid(sum relu(h)*v + c).
// LDS 160 KB = 2 x (As 16 KB + Bs 64 KB), double-buffered, ONE barrier/K-iter.
// After writing its logits tile, each block signals done[b]; the LAST block of
// a sample runs that sample's exact top-k mean inline (overlaps the gemm
// straggler round -> no separate kernel, no full-grid dependency).
// ---------------------------------------------------------------------------
__device__ __forceinline__ int sw_idx(int row, int e) {  // elem idx into [row][64]
    return row * 64 + (((e >> 3) ^ (row & 7)) << 3) + (e & 7);
}

__global__ __launch_bounds__(512, 2) void gemm_fused(const float* __restrict__ A,
                                                     const bf16* __restrict__ W1T,
                                                     const float* __restrict__ b1,
                                                     const float* __restrict__ v,
                                                     const int* __restrict__ tiles,
                                                     const int* __restrict__ seq_len,
                                                     int* __restrict__ done,
                                                     float* __restrict__ logits,
                                                     float* __restrict__ out) {
    __shared__ bf16 smem[2][(128 + 512) * 64];  // 2 x 80 KB = 160 KB (CU max)

    const int nact = tiles[0];
    if ((int)blockIdx.x >= nact) return;         // dead tile: no HBM traffic
    const int tileid = tiles[1 + blockIdx.x];
    const int m0 = tileid * 128;
    const int bsmp = tileid >> 4;                // owning sample

    const int t = threadIdx.x;
    const int wave = t >> 6, lane = t & 63;
    const int q = lane >> 4, l15 = lane & 15;
    const int wm = wave >> 2, wn = wave & 3;   // 2 x 4 wave grid, wave tile 64x128

    const int arow = t >> 2, ac = t & 3;
    const float* agp = A + (size_t)(m0 + arow) * K_TOT + ac * 4;

    // B async staging: lane -> n-row wave*64 + (lane>>3), global 16B chunk
    // XOR-permuted so linear LDS (base + lane*16) ends up swizzled.
    const int bl_row = wave * 64 + (lane >> 3);
    const int bl_chunk = (lane & 7) ^ ((lane >> 3) & 7);
    const bf16* bgp = W1T + (size_t)bl_row * K_TOT + bl_chunk * 8;

    f32x4 acc[4][8] = {};
    float4 av[4];

    auto loadA = [&](int k0) {
#pragma unroll
        for (int p = 0; p < 4; p++) av[p] = *(const float4*)(agp + k0 + p * 16);
    };
    auto asyncB = [&](int k0, int b) {
        bf16* bs = smem[b] + 128 * 64;
#pragma unroll
        for (int j = 0; j < 8; j++)
            async16(bgp + k0 + (size_t)j * 8 * K_TOT, bs + (wave * 64 + j * 8) * 64);
    };
    auto writeA = [&](int b) {
        bf16* as = smem[b];
#pragma unroll
        for (int p = 0; p < 4; p++) {
            bf16x4 w;
            w[0] = (bf16)av[p].x; w[1] = (bf16)av[p].y;
            w[2] = (bf16)av[p].z; w[3] = (bf16)av[p].w;
            int chunk = 2 * p + (ac >> 1);                 // global 8-elem chunk
            int idx = arow * 64 + ((chunk ^ (arow & 7)) << 3) + (ac & 1) * 4;
            *(bf16x4*)(&as[idx]) = w;
        }
    };
    auto mfma_phase = [&](int b) {
        const bf16* as = smem[b];
        const bf16* bs = smem[b] + 128 * 64;
#pragma unroll
        for (int kk = 0; kk < 64; kk += 32) {
            const int e = kk + q * 8;
            bf16x8 af[4], bfv[8];
#pragma unroll
            for (int mi = 0; mi < 4; mi++)
                af[mi] = *(const bf16x8*)(&as[sw_idx(wm * 64 + mi * 16 + l15, e)]);
#pragma unroll
            for (int ni = 0; ni < 8; ni++)
                bfv[ni] = *(const bf16x8*)(&bs[sw_idx(wn * 128 + ni * 16 + l15, e)]);
#pragma unroll
            for (int mi = 0; mi < 4; mi++)
#pragma unroll
                for (int ni = 0; ni < 8; ni++)
                    acc[mi][ni] = __builtin_amdgcn_mfma_f32_16x16x32_bf16(
                        af[mi], bfv[ni], acc[mi][ni], 0, 0, 0);
        }
    };

    // ---- preload k=0 into buffer 0 ----
    loadA(0);
    asyncB(0, 0);
    writeA(0);          // compiler: vmcnt(8) -> waits A only, B stays in flight
    __syncthreads();    // drains B(0)

#pragma unroll 1
    for (int k = 0; k < 16; k++) {
        const int buf = k & 1, nxt = buf ^ 1;
        if (k < 15) {
            loadA((k + 1) * 64);        // A(k+1) -> VGPR   (overlaps MFMA below)
            asyncB((k + 1) * 64, nxt);  // B(k+1) -> LDS async
        }
        mfma_phase(buf);             // ~2500 cyc/CU: covers all load latency
        if (k < 15) writeA(nxt);     // vmcnt wait lands after MFMA -> ~free
        __syncthreads();             // single barrier per iter; drains B(k+1)
    }

    // ---- Epilogue: logit[m] = sigmoid( sum_cols relu(acc + b1)*v + c ) ----
    float bb[8], vv[8];
#pragma unroll
    for (int ni = 0; ni < 8; ni++) {
        int col = wn * 128 + ni * 16 + l15;
        bb[ni] = b1[col];
        vv[ni] = v[col];
    }
    const float cconst = v[512];

    __syncthreads();
    float* part = (float*)smem;      // [128][4] per-row partials per wn

#pragma unroll
    for (int mi = 0; mi < 4; mi++) {
#pragma unroll
        for (int r = 0; r < 4; r++) {
            float s = 0.f;
#pragma unroll
            for (int ni = 0; ni < 8; ni++)
                s += fmaxf(acc[mi][ni][r] + bb[ni], 0.f) * vv[ni];
            s += __shfl_xor(s, 1);
            s += __shfl_xor(s, 2);
            s += __shfl_xor(s, 4);
            s += __shfl_xor(s, 8);
            if (l15 == 0) {
                int row = wm * 64 + mi * 16 + q * 4 + r;
                part[row * 4 + wn] = s;
            }
        }
    }
    __syncthreads();
    if (t < 128) {
        float s = part[t * 4] + part[t * 4 + 1] + part[t * 4 + 2] + part[t * 4 + 3] + cconst;
        logits[m0 + t] = 1.f / (1.f + __expf(-s));
    }

    // ---- completion protocol: last block of the sample runs its top-k ----
    const int L = seq_len[bsmp];
    const int nb = (L + 127) >> 7;               // live tiles of this sample

    // LDS carve-outs (all within the 160 KB smem; previous uses are dead)
    float* vals  = (float*)smem;                 // [2048]
    int*   redi  = (int*)(vals + 2048);          // [2][8] round-alternating
    unsigned* mnx = (unsigned*)(redi + 16);      // [16] min/max scratch
    float* redf  = (float*)(mnx + 16);           // [8]
    int*   wflag = (int*)(redf + 8);

    __syncthreads();                             // logits stores done block-wide
    if (t == 0) {
        __threadfence();                         // release: publish logits
        int old = atomicAdd(&done[bsmp], 1);
        int win = (old == nb - 1);
        if (win) __threadfence();                // acquire: see others' logits
        *wflag = win;
    }
    __syncthreads();
    if (!*wflag) return;

    // ---- exact top-k mean for sample bsmp (k = L/16 + 1) ----
    const int kk = (L >> 4) + 1;
    const float* p = logits + bsmp * T_SEQ;

    // stage + min/max in one pass (uint order == float order: all in (0,1))
    unsigned mn = 0x3f800000u, mx = 0u;          // 1.0f > all, 0 < all
    for (int i = t; i < L; i += 512) {
        float x = p[i];
        vals[i] = x;
        unsigned u = __float_as_uint(x);
        mn = min(mn, u); mx = max(mx, u);
    }
#pragma unroll
    for (int m = 32; m >= 1; m >>= 1) {
        mn = min(mn, (unsigned)__shfl_xor((int)mn, m));
        mx = max(mx, (unsigned)__shfl_xor((int)mx, m));
    }
    if (lane == 0) { mnx[wave] = mn; mnx[8 + wave] = mx; }
    __syncthreads();
    unsigned lo = mnx[0], hi = mnx[8];
#pragma unroll
    for (int w8 = 1; w8 < 8; w8++) {
        lo = min(lo, mnx[w8]); hi = max(hi, mnx[8 + w8]);
    }
    __syncthreads();    // mnx reads done before redi[0] writes (same region safety)

    // 2-probe bisection on float bits: ~log3 rounds, 1 barrier each.
    // Invariant: count(>= float(lo)) >= kk.
    int rb = 0;
    while (lo < hi) {
        unsigned w = hi - lo;
        unsigned t1 = w / 3u + 1u;
        unsigned m1 = lo + t1;                   // lo < m1 <= hi
        unsigned m2 = lo + (w - w / 3u);         // m1 <= m2 <= hi
        if (m2 < m1) m2 = m1;
        float f1 = __uint_as_float(m1), f2 = __uint_as_float(m2);
        int c1 = 0, c2 = 0;
        for (int i = t; i < L; i += 512) {
            float x = vals[i];
            c1 += (x >= f1) ? 1 : 0;
            c2 += (x >= f2) ? 1 : 0;
        }
        int packed = (c1 << 12) | c2;            // counts <= 2048 < 4096 each
#pragma unroll
        for (int m = 32; m >= 1; m >>= 1) packed += __shfl_xor(packed, m);
        if (lane == 0) redi[(rb & 1) * 8 + wave] = packed;
        __syncthreads();
        int tot = 0;
#pragma unroll
        for (int w8 = 0; w8 < 8; w8++) tot += redi[(rb & 1) * 8 + w8];
        int C2 = tot & 0xFFF, C1 = tot >> 12;
        if (C2 >= kk)      { lo = m2; }
        else if (C1 >= kk) { lo = m1; hi = m2 - 1; }
        else               { hi = m1 - 1; }
        rb++;
        // no extra barrier: next round writes the OTHER redi buffer
    }
    const float thr = __uint_as_float(lo);       // exact k-th largest value

    int cg = 0; float sg = 0.f;
    for (int i = t; i < L; i += 512) {
        float x = vals[i];
        if (x > thr) { cg += 1; sg += x; }
    }
#pragma unroll
    for (int m = 32; m >= 1; m >>= 1) {
        cg += __shfl_xor(cg, m);
        sg += __shfl_xor(sg, m);
    }
    if (lane == 0) { redi[(rb & 1) * 8 + wave] = cg; redf[wave] = sg; }
    __syncthreads();
    if (t == 0) {
        int cgt = 0; float sgt = 0.f;
#pragma unroll
        for (int w8 = 0; w8 < 8; w8++) { cgt += redi[(rb & 1) * 8 + w8]; sgt += redf[w8]; }
        out[bsmp] = (sgt + (float)(kk - cgt) * thr) / (float)kk;
    }
}

// ---------------------------------------------------------------------------
extern "C" void kernel_launch(void* const* d_in, const int* in_sizes, int n_in,
                              void* d_out, int out_size, void* d_ws, size_t ws_size,
                              hipStream_t stream) {
    const float* avf = (const float*)d_in[0];
    const float* W1  = (const float*)d_in[1];
    const float* b1  = (const float*)d_in[2];
    const float* W2  = (const float*)d_in[3];
    const float* b2  = (const float*)d_in[4];
    const float* W3  = (const float*)d_in[5];
    const float* b3  = (const float*)d_in[6];
    const int* seq_len = (const int*)d_in[7];
    float* out = (float*)d_out;

    char* ws = (char*)d_ws;
    bf16*  W1T    = (bf16*)ws;                          // 1 MB
    float* v      = (float*)(ws + (1 << 20));           // 513 floats
    int*   tiles  = (int*)(ws + (1 << 20) + 4096);      // 1 + 512 ints
    int*   done   = (int*)(ws + (1 << 20) + 8192);      // 32 ints
    float* logits = (float*)(ws + (1 << 20) + 12288);   // 256 KB

    transpose_prep<<<dim3(32, 16), 256, 0, stream>>>(W1, W1T, W2, b2, W3, b3,
                                                     seq_len, v, tiles, done);
    gemm_fused<<<512, 512, 0, stream>>>(avf, W1T, b1, v, tiles, seq_len, done,
                                        logits, out);
}

// Round 3
// 397.567 us; speedup vs baseline: 1.0680x; 1.0354x over previous
//
#include <hip/hip_runtime.h>

typedef __bf16 bf16;
typedef __bf16 bf16x4 __attribute__((ext_vector_type(4)));
typedef __bf16 bf16x8 __attribute__((ext_vector_type(8)));
typedef float f32x4 __attribute__((ext_vector_type(4)));

#define K_TOT 1024    // D_IN
#define N_TOT 512     // H1
#define T_SEQ 2048
#define NB 32
#define M_TILE 160    // rows per gemm block: E[sum ceil(L/160)] ~ 221 <= 256 CUs -> 1 round
#define MAX_J 13      // ceil(2048/160)
#define ROW_MAX (NB * T_SEQ - 1)

// ---------------------------------------------------------------------------
// async global->LDS, 16B per lane. LDS dest = wave-uniform base + lane*16.
// ---------------------------------------------------------------------------
__device__ __forceinline__ void async16(const void* g, void* l) {
    __builtin_amdgcn_global_load_lds(
        (const __attribute__((address_space(1))) unsigned int*)g,
        (__attribute__((address_space(3))) unsigned int*)l, 16, 0, 0);
}

// ---------------------------------------------------------------------------
// Kernel 0 (merged): W1 [1024,512] fp32 -> W1T [512,1024] bf16, AND (block 0)
// prep: fold layers 2+3 into v[], build compacted live-tile list, zero
// per-sample completion counters.
// Tile (b,j) covers sample-b rows [j*160, j*160+160); live iff j*160 < L_b.
// tiles[0] = live count, tiles[1..] = (b<<4)|j  (j <= 12 fits 4 bits).
// ---------------------------------------------------------------------------
__global__ __launch_bounds__(256) void transpose_prep(
        const float* __restrict__ W1, bf16* __restrict__ W1T,
        const float* __restrict__ W2, const float* __restrict__ b2,
        const float* __restrict__ W3, const float* __restrict__ b3,
        const int* __restrict__ seq_len,
        float* __restrict__ v, int* __restrict__ tiles, int* __restrict__ done) {
    __shared__ float tile[32][33];
    __shared__ int nb2[32], off2[32];
    const int t = threadIdx.x;
    const int k0 = blockIdx.x * 32;
    const int n0 = blockIdx.y * 32;
#pragma unroll
    for (int p = 0; p < 4; p++) {
        int kl = p * 8 + (t >> 5);
        int nl = t & 31;
        tile[kl][nl] = W1[(k0 + kl) * 512 + n0 + nl];
    }
    __syncthreads();
#pragma unroll
    for (int p = 0; p < 4; p++) {
        int nl = p * 8 + (t >> 5);
        int kl = t & 31;
        W1T[(n0 + nl) * 1024 + k0 + kl] = (bf16)tile[kl][nl];
    }

    if (blockIdx.x == 0 && blockIdx.y == 0) {   // block-uniform branch
        // v[h] = sum_c W2[h][c]*W3[c];  v[512] = b2.W3 + b3
        for (int h = t; h < 512; h += 256) {
            float s = 0.f;
#pragma unroll
            for (int c = 0; c < 32; c++) s += W2[h * 32 + c] * W3[c];
            v[h] = s;
        }
        if (t == 0) {
            float cc = b3[0];
            for (int c = 0; c < 32; c++) cc += b2[c] * W3[c];
            v[512] = cc;
        }
        if (t < 32) {
            nb2[t] = (seq_len[t] + M_TILE - 1) / M_TILE;   // ceil(L/160), in [1,13]
            done[t] = 0;                                   // completion counters
        }
        __syncthreads();
        if (t == 0) {
            int a = 0;
            for (int i = 0; i < 32; i++) { off2[i] = a; a += nb2[i]; }
            tiles[0] = a;
        }
        __syncthreads();
        for (int idx = t; idx < 512; idx += 256) {
            int b = idx >> 4, j = idx & 15;
            if (j < nb2[b]) tiles[1 + off2[b] + j] = (b << 4) | j;
        }
    }
}

// ---------------------------------------------------------------------------
// Kernel 1 (fused gemm + MLP epilogue + per-sample top-k):
// per block: M_TILE=160 rows x full N=512; logits = sigmoid(sum relu(h)*v+c).
// LDS 148 KB: A single-buffered 20 KB (next tile's A rides in VGPRs through
// the MFMA phase; its LDS write lands behind the barrier, +1 barrier/iter)
// + B double-buffered 2x64 KB via global_load_lds (the latency that matters).
// ~221 live tiles <= 256 CUs -> single dispatch round (was 271 -> 2 rounds).
// Last block of each sample runs that sample's exact top-k mean inline.
// ---------------------------------------------------------------------------
__device__ __forceinline__ int sw_idx(int row, int e) {  // elem idx into [row][64]
    return row * 64 + (((e >> 3) ^ (row & 7)) << 3) + (e & 7);
}

__global__ __launch_bounds__(512, 2) void gemm_fused(const float* __restrict__ A,
                                                     const bf16* __restrict__ W1T,
                                                     const float* __restrict__ b1,
                                                     const float* __restrict__ v,
                                                     const int* __restrict__ tiles,
                                                     const int* __restrict__ seq_len,
                                                     int* __restrict__ done,
                                                     float* __restrict__ logits,
                                                     float* __restrict__ out) {
    // 160*64 (A) + 2 * 512*64 (B) bf16 = 148 KB
    __shared__ bf16 smem[M_TILE * 64 + 2 * N_TOT * 64];
    bf16* As = smem;
    bf16* Bs0 = smem + M_TILE * 64;
    bf16* Bs1 = Bs0 + N_TOT * 64;

    const int nact = tiles[0];
    if ((int)blockIdx.x >= nact) return;         // dead slot
    const int tileid = tiles[1 + blockIdx.x];
    const int bsmp = tileid >> 4;                // owning sample
    const int jj = tileid & 15;                  // tile index within sample
    const int m0 = bsmp * T_SEQ + jj * M_TILE;   // first global row

    const int t = threadIdx.x;
    const int wave = t >> 6, lane = t & 63;
    const int q = lane >> 4, l15 = lane & 15;
    const int wm = wave >> 2, wn = wave & 3;     // 2 x 4 wave grid; wm tile 80 rows

    // A staging: thread t handles float4 col c16 = t&15 of rows r0+p*32.
    // 16 lanes cover one row's 64-float K-chunk = 256B contiguous runs.
    const int c16 = t & 15, r0 = t >> 4;
    const float* agp[5];
#pragma unroll
    for (int p = 0; p < 5; p++) {
        int grow = m0 + r0 + p * 32;
        if (grow > ROW_MAX) grow = ROW_MAX;      // last tile of last sample: clamp in-bounds
        agp[p] = A + (size_t)grow * K_TOT + c16 * 4;
    }

    // B async staging: lane -> n-row wave*64 + (lane>>3), global 16B chunk
    // XOR-permuted so linear LDS (base + lane*16) ends up swizzled.
    const int bl_row = wave * 64 + (lane >> 3);
    const int bl_chunk = (lane & 7) ^ ((lane >> 3) & 7);
    const bf16* bgp = W1T + (size_t)bl_row * K_TOT + bl_chunk * 8;

    f32x4 acc[5][8] = {};
    float4 av[5];

    auto loadA = [&](int k0) {
#pragma unroll
        for (int p = 0; p < 5; p++) av[p] = *(const float4*)(agp[p] + k0);
    };
    auto asyncB = [&](int k0, bf16* bs) {
#pragma unroll
        for (int j = 0; j < 8; j++)
            async16(bgp + k0 + (size_t)j * 8 * K_TOT, bs + (wave * 64 + j * 8) * 64);
    };
    auto writeA = [&]() {
#pragma unroll
        for (int p = 0; p < 5; p++) {
            bf16x4 w;
            w[0] = (bf16)av[p].x; w[1] = (bf16)av[p].y;
            w[2] = (bf16)av[p].z; w[3] = (bf16)av[p].w;
            int row = r0 + p * 32;
            int chunk = c16 >> 1;                 // global 8-elem chunk
            int idx = row * 64 + ((chunk ^ (row & 7)) << 3) + (c16 & 1) * 4;
            *(bf16x4*)(&As[idx]) = w;
        }
    };
    auto mfma_phase = [&](const bf16* bs) {
#pragma unroll
        for (int kk = 0; kk < 64; kk += 32) {
            const int e = kk + q * 8;
            bf16x8 af[5];
#pragma unroll
            for (int mi = 0; mi < 5; mi++)
                af[mi] = *(const bf16x8*)(&As[sw_idx(wm * 80 + mi * 16 + l15, e)]);
#pragma unroll
            for (int nh = 0; nh < 8; nh += 4) {   // ni-halves: caps VGPR pressure
                bf16x8 bfv[4];
#pragma unroll
                for (int ni = 0; ni < 4; ni++)
                    bfv[ni] = *(const bf16x8*)(&bs[sw_idx(wn * 128 + (nh + ni) * 16 + l15, e)]);
#pragma unroll
                for (int mi = 0; mi < 5; mi++)
#pragma unroll
                    for (int ni = 0; ni < 4; ni++)
                        acc[mi][nh + ni] = __builtin_amdgcn_mfma_f32_16x16x32_bf16(
                            af[mi], bfv[ni], acc[mi][nh + ni], 0, 0, 0);
            }
        }
    };

    // ---- preload k=0 ----
    loadA(0);
    asyncB(0, Bs0);
    writeA();           // compiler: vmcnt(8) -> waits A only, B stays in flight
    __syncthreads();    // drains B(0); A(0) visible

#pragma unroll 1
    for (int k = 0; k < 16; k++) {
        bf16* bcur = (k & 1) ? Bs1 : Bs0;
        bf16* bnxt = (k & 1) ? Bs0 : Bs1;
        if (k < 15) {
            loadA((k + 1) * 64);        // A(k+1) -> VGPR (overlaps MFMA below)
            asyncB((k + 1) * 64, bnxt); // B(k+1) -> LDS async
        }
        mfma_phase(bcur);               // covers load latency
        __syncthreads();                // waves done reading As/B(k); drains B(k+1)
        if (k < 15) {
            writeA();                   // overwrite single A buffer with A(k+1)
            __syncthreads();            // A(k+1) visible
        }
    }

    // ---- Epilogue: logit[m] = sigmoid( sum_cols relu(acc + b1)*v + c ) ----
    float bb[8], vv[8];
#pragma unroll
    for (int ni = 0; ni < 8; ni++) {
        int col = wn * 128 + ni * 16 + l15;
        bb[ni] = b1[col];
        vv[ni] = v[col];
    }
    const float cconst = v[512];

    float* part = (float*)smem;      // [160][4] per-row partials per wn (aliases As)

#pragma unroll
    for (int mi = 0; mi < 5; mi++) {
#pragma unroll
        for (int r = 0; r < 4; r++) {
            float s = 0.f;
#pragma unroll
            for (int ni = 0; ni < 8; ni++)
                s += fmaxf(acc[mi][ni][r] + bb[ni], 0.f) * vv[ni];
            s += __shfl_xor(s, 1);
            s += __shfl_xor(s, 2);
            s += __shfl_xor(s, 4);
            s += __shfl_xor(s, 8);
            if (l15 == 0) {
                int row = wm * 80 + mi * 16 + q * 4 + r;
                part[row * 4 + wn] = s;
            }
        }
    }
    __syncthreads();
    if (t < M_TILE && jj * M_TILE + t < T_SEQ) {   // guard: don't cross into next sample
        float s = part[t * 4] + part[t * 4 + 1] + part[t * 4 + 2] + part[t * 4 + 3] + cconst;
        logits[m0 + t] = 1.f / (1.f + __expf(-s));
    }

    // ---- completion protocol: last block of the sample runs its top-k ----
    const int L = seq_len[bsmp];
    const int nb = (L + M_TILE - 1) / M_TILE;    // live tiles of this sample

    float* vals  = (float*)smem;                 // [2048]
    int*   redi  = (int*)(vals + 2048);          // [2][8] round-alternating
    unsigned* mnx = (unsigned*)(redi + 16);      // [16] min/max scratch
    float* redf  = (float*)(mnx + 16);           // [8]
    int*   wflag = (int*)(redf + 8);

    __syncthreads();                             // logits stores done block-wide
    if (t == 0) {
        __threadfence();                         // release: publish logits
        int old = atomicAdd(&done[bsmp], 1);
        int win = (old == nb - 1);
        if (win) __threadfence();                // acquire: see others' logits
        *wflag = win;
    }
    __syncthreads();
    if (!*wflag) return;

    // ---- exact top-k mean for sample bsmp (k = L/16 + 1) ----
    const int kk = (L >> 4) + 1;
    const float* p = logits + bsmp * T_SEQ;

    // stage + min/max in one pass (uint order == float order: all in (0,1))
    unsigned mn = 0x3f800000u, mx = 0u;          // 1.0f > all, 0 < all
    for (int i = t; i < L; i += 512) {
        float x = p[i];
        vals[i] = x;
        unsigned u = __float_as_uint(x);
        mn = min(mn, u); mx = max(mx, u);
    }
#pragma unroll
    for (int m = 32; m >= 1; m >>= 1) {
        mn = min(mn, (unsigned)__shfl_xor((int)mn, m));
        mx = max(mx, (unsigned)__shfl_xor((int)mx, m));
    }
    if (lane == 0) { mnx[wave] = mn; mnx[8 + wave] = mx; }
    __syncthreads();
    unsigned lo = mnx[0], hi = mnx[8];
#pragma unroll
    for (int w8 = 1; w8 < 8; w8++) {
        lo = min(lo, mnx[w8]); hi = max(hi, mnx[8 + w8]);
    }
    __syncthreads();    // mnx reads done before redi[0] writes

    // 2-probe bisection on float bits: ~log3 rounds, 1 barrier each.
    // Invariant: count(>= float(lo)) >= kk.
    int rb = 0;
    while (lo < hi) {
        unsigned w = hi - lo;
        unsigned t1 = w / 3u + 1u;
        unsigned m1 = lo + t1;                   // lo < m1 <= hi
        unsigned m2 = lo + (w - w / 3u);         // m1 <= m2 <= hi
        if (m2 < m1) m2 = m1;
        float f1 = __uint_as_float(m1), f2 = __uint_as_float(m2);
        int c1 = 0, c2 = 0;
        for (int i = t; i < L; i += 512) {
            float x = vals[i];
            c1 += (x >= f1) ? 1 : 0;
            c2 += (x >= f2) ? 1 : 0;
        }
        int packed = (c1 << 12) | c2;            // counts <= 2048 < 4096 each
#pragma unroll
        for (int m = 32; m >= 1; m >>= 1) packed += __shfl_xor(packed, m);
        if (lane == 0) redi[(rb & 1) * 8 + wave] = packed;
        __syncthreads();
        int tot = 0;
#pragma unroll
        for (int w8 = 0; w8 < 8; w8++) tot += redi[(rb & 1) * 8 + w8];
        int C2 = tot & 0xFFF, C1 = tot >> 12;
        if (C2 >= kk)      { lo = m2; }
        else if (C1 >= kk) { lo = m1; hi = m2 - 1; }
        else               { hi = m1 - 1; }
        rb++;
        // no extra barrier: next round writes the OTHER redi buffer
    }
    const float thr = __uint_as_float(lo);       // exact k-th largest value

    int cg = 0; float sg = 0.f;
    for (int i = t; i < L; i += 512) {
        float x = vals[i];
        if (x > thr) { cg += 1; sg += x; }
    }
#pragma unroll
    for (int m = 32; m >= 1; m >>= 1) {
        cg += __shfl_xor(cg, m);
        sg += __shfl_xor(sg, m);
    }
    if (lane == 0) { redi[(rb & 1) * 8 + wave] = cg; redf[wave] = sg; }
    __syncthreads();
    if (t == 0) {
        int cgt = 0; float sgt = 0.f;
#pragma unroll
        for (int w8 = 0; w8 < 8; w8++) { cgt += redi[(rb & 1) * 8 + w8]; sgt += redf[w8]; }
        out[bsmp] = (sgt + (float)(kk - cgt) * thr) / (float)kk;
    }
}

// ---------------------------------------------------------------------------
extern "C" void kernel_launch(void* const* d_in, const int* in_sizes, int n_in,
                              void* d_out, int out_size, void* d_ws, size_t ws_size,
                              hipStream_t stream) {
    const float* avf = (const float*)d_in[0];
    const float* W1  = (const float*)d_in[1];
    const float* b1  = (const float*)d_in[2];
    const float* W2  = (const float*)d_in[3];
    const float* b2  = (const float*)d_in[4];
    const float* W3  = (const float*)d_in[5];
    const float* b3  = (const float*)d_in[6];
    const int* seq_len = (const int*)d_in[7];
    float* out = (float*)d_out;

    char* ws = (char*)d_ws;
    bf16*  W1T    = (bf16*)ws;                          // 1 MB
    float* v      = (float*)(ws + (1 << 20));           // 513 floats
    int*   tiles  = (int*)(ws + (1 << 20) + 4096);      // 1 + 416 ints
    int*   done   = (int*)(ws + (1 << 20) + 8192);      // 32 ints
    float* logits = (float*)(ws + (1 << 20) + 12288);   // 256 KB

    transpose_prep<<<dim3(32, 16), 256, 0, stream>>>(W1, W1T, W2, b2, W3, b3,
                                                     seq_len, v, tiles, done);
    gemm_fused<<<NB * MAX_J, 512, 0, stream>>>(avf, W1T, b1, v, tiles, seq_len,
                                               done, logits, out);
}